// Round 3
// baseline (1708.145 us; speedup 1.0000x reference)
//
#include <hip/hip_runtime.h>
#include <hip/hip_bf16.h>

typedef __attribute__((ext_vector_type(8))) short bf16x8_t;
typedef __attribute__((ext_vector_type(4))) float f32x4_t;

__device__ __forceinline__ unsigned bfr(float x) {
  unsigned u = __builtin_bit_cast(unsigned, x);
  return (u + 0x7fffu + ((u >> 16) & 1u)) >> 16;
}
__device__ __forceinline__ unsigned pk2(float lo, float hi) {
  return bfr(lo) | (bfr(hi) << 16);
}

// ---------------------------------------------------------------------------
// Conv (3x3, stride 2, pad 1) + bias + relu, per-channel sum/sumsq stats.
// BN of the INPUT is fused algebraically: x_norm = x*sc + sh, with sc folded
// into the LDS weights and the sh-term reduced to 4 border-class scalars
// (only oh==0 / ow==0 pixels lose taps for stride-2 pad-1 even dims).
// Input x is the RAW (pre-BN) relu output of the previous conv.
// ---------------------------------------------------------------------------
template<int CIN, int H, int W, bool BNIN>
__global__ __launch_bounds__(256) void convk(
    const float* __restrict__ x, const float* __restrict__ wgt,
    const float* __restrict__ bias,
    const float* __restrict__ instats,
    const float* __restrict__ ing, const float* __restrict__ inb,
    float* __restrict__ y, float* __restrict__ stats)
{
  constexpr int HO = H / 2, WO = W / 2, N = HO * WO;
  const int bc = blockIdx.x;
  const int b = bc / 24, co = bc % 24;
  const int tid = threadIdx.x;
  __shared__ float wsm[CIN * 9];
  __shared__ float scls[CIN];
  __shared__ float shls[CIN];
  __shared__ float shs[4];

  if (BNIN && tid < CIN) {
    const float cnt = 64.f * H * W;
    const float m = instats[tid] / cnt;
    const float v = instats[24 + tid] / cnt - m * m;
    const float s = rsqrtf(v + 1e-5f) * ing[tid];
    scls[tid] = s;
    shls[tid] = inb[tid] - m * s;
  }
  __syncthreads();
  if (tid < CIN * 9)
    wsm[tid] = wgt[co * CIN * 9 + tid] * (BNIN ? scls[tid / 9] : 1.f);
  if (tid < 4) {
    float s = 0.f;
    if (BNIN) {
      #pragma unroll
      for (int ci = 0; ci < CIN; ++ci) {
        float a = 0.f;
        for (int r = (tid & 1); r < 3; ++r)
          for (int c = ((tid >> 1) & 1); c < 3; ++c)
            a += wgt[co * CIN * 9 + ci * 9 + r * 3 + c];
        s += shls[ci] * a;
      }
    }
    shs[tid] = s;
  }
  __syncthreads();

  const float bv = bias[co];
  const float* xb = x + (size_t)b * CIN * H * W;
  float bsum = 0.f, bsq = 0.f;
  for (int p = tid; p < N; p += 256) {
    const int oh = p / WO, ow = p - oh * WO;
    const int ih0 = oh * 2 - 1, iw0 = ow * 2 - 1;
    float acc = bv + shs[(oh == 0 ? 1 : 0) + (ow == 0 ? 2 : 0)];
    if (oh > 0 && ow > 0) {
      const float* xp = xb + ih0 * W + iw0;
      #pragma unroll
      for (int ci = 0; ci < CIN; ++ci) {
        const float* wp = wsm + ci * 9;
        #pragma unroll
        for (int r = 0; r < 3; ++r)
          #pragma unroll
          for (int s2 = 0; s2 < 3; ++s2)
            acc += xp[r * W + s2] * wp[r * 3 + s2];
        xp += H * W;
      }
    } else {
      #pragma unroll
      for (int ci = 0; ci < CIN; ++ci) {
        const float* xp = xb + (size_t)ci * H * W;
        const float* wp = wsm + ci * 9;
        #pragma unroll
        for (int r = 0; r < 3; ++r) {
          const int ih = ih0 + r;
          if (ih >= 0) {
            #pragma unroll
            for (int s2 = 0; s2 < 3; ++s2) {
              const int iw = iw0 + s2;
              if (iw >= 0) acc += xp[ih * W + iw] * wp[r * 3 + s2];
            }
          }
        }
      }
    }
    const float v = fmaxf(acc, 0.f);
    y[(size_t)(b * 24 + co) * N + p] = v;
    bsum += v; bsq += v * v;
  }
  #pragma unroll
  for (int off = 32; off > 0; off >>= 1) {
    bsum += __shfl_down(bsum, off, 64);
    bsq  += __shfl_down(bsq,  off, 64);
  }
  __shared__ float rs[4], rq[4];
  const int wv = tid >> 6, ln = tid & 63;
  if (ln == 0) { rs[wv] = bsum; rq[wv] = bsq; }
  __syncthreads();
  if (tid == 0) {
    atomicAdd(&stats[co],      rs[0] + rs[1] + rs[2] + rs[3]);
    atomicAdd(&stats[24 + co], rq[0] + rq[1] + rq[2] + rq[3]);
  }
}

// ---------------------------------------------------------------------------
// Build A = o @ Wi, B = o @ Wj (BN of x4 fused into o), Cq = qst@Wq + gb1.
// ---------------------------------------------------------------------------
__global__ __launch_bounds__(256) void build_ab(
    const float* __restrict__ x4, const float* __restrict__ stats4,
    const float* __restrict__ g4, const float* __restrict__ b4,
    const float* __restrict__ gw1,
    float* __restrict__ A, float* __restrict__ Bm)
{
  const int bp = blockIdx.x;
  const int b = bp >> 6, p = bp & 63;
  const int t = threadIdx.x;
  __shared__ float o[26];
  if (t < 24) {
    const float m = stats4[t] * (1.f / 4096.f);
    const float v = stats4[24 + t] * (1.f / 4096.f) - m * m;
    const float sc = rsqrtf(v + 1e-5f) * g4[t];
    const float sh = b4[t] - m * sc;
    o[t] = x4[(size_t)(b * 24 + t) * 64 + p] * sc + sh;
  } else if (t == 24) o[24] = (float)(p >> 3);
  else if (t == 25) o[25] = (float)(p & 7);
  __syncthreads();
  float a = 0.f, bb2 = 0.f;
  #pragma unroll
  for (int c = 0; c < 26; ++c) {
    a   += o[c] * gw1[c * 256 + t];
    bb2 += o[c] * gw1[(26 + c) * 256 + t];
  }
  A[(size_t)bp * 256 + t]  = a;
  Bm[(size_t)bp * 256 + t] = bb2;
}

__global__ __launch_bounds__(256) void build_cq(
    const float* __restrict__ qst, const float* __restrict__ gw1,
    const float* __restrict__ gb1, float* __restrict__ Cq)
{
  const int b = blockIdx.x, t = threadIdx.x;
  float a = gb1[t];
  #pragma unroll
  for (int c = 0; c < 11; ++c) a += qst[b * 11 + c] * gw1[(52 + c) * 256 + t];
  Cq[b * 256 + t] = a;
}

// ---------------------------------------------------------------------------
// Transpose-convert the 3 W matrices (fp32 [k][n]) -> bf16 [n][k]. Grid 192.
// ---------------------------------------------------------------------------
__global__ __launch_bounds__(256) void wt_convert3(
    const float* __restrict__ W2, const float* __restrict__ W3,
    const float* __restrict__ W4, unsigned short* __restrict__ wt)
{
  const int which = blockIdx.x >> 6;
  const float* W = which == 0 ? W2 : which == 1 ? W3 : W4;
  unsigned short* o = wt + (size_t)which * 65536;
  __shared__ float ts[32][33];
  const int blk = blockIdx.x & 63;
  const int k0 = (blk & 7) * 32, n0 = (blk >> 3) * 32;
  const int t = threadIdx.x;
  const int r = t >> 3, c4 = (t & 7) * 4;
  const float4 v = *(const float4*)(W + (size_t)(k0 + r) * 256 + n0 + c4);
  ts[r][c4 + 0] = v.x; ts[r][c4 + 1] = v.y;
  ts[r][c4 + 2] = v.z; ts[r][c4 + 3] = v.w;
  __syncthreads();
  uint2 ov;
  ov.x = pk2(ts[c4 + 0][r], ts[c4 + 1][r]);
  ov.y = pk2(ts[c4 + 2][r], ts[c4 + 3][r]);
  *(uint2*)(o + (size_t)(n0 + r) * 256 + k0 + c4) = ov;
}

// ---------------------------------------------------------------------------
// Pair MLP via MFMA. 4 waves/block, 64 rows x 256 cols per block.
// W fragments live in REGISTERS (global loads, prefetch depth 2) — no W
// staging, no per-chunk barriers (2 barriers/layer). h in 32KB swizzled LDS.
// ---------------------------------------------------------------------------
__global__ __launch_bounds__(256) void pair_mfma(
    const float* __restrict__ A, const float* __restrict__ Bm,
    const float* __restrict__ Cq,
    const unsigned short* __restrict__ wt2, const float* __restrict__ b2,
    const unsigned short* __restrict__ wt3, const float* __restrict__ b3,
    const unsigned short* __restrict__ wt4, const float* __restrict__ b4,
    float* __restrict__ g)
{
  __shared__ __align__(16) unsigned short hsm[64 * 256];   // 32 KB
  __shared__ float gpart[256];

  const int tid = threadIdx.x;
  int bid = blockIdx.x;
  bid = (bid & 7) * 512 + (bid >> 3);      // XCD swizzle (4096 = 8*512)
  const int b = bid >> 6, local = bid & 63;
  const int lane = tid & 63, cg = tid >> 6;
  const int l15 = lane & 15, l4 = lane >> 4;
  char* hbase = (char*)hsm;

  // ---- build h1 = relu(A_i + B_j + Cq) bf16, swizzled. i=row m, j=local.
  {
    const int m = tid >> 2, seg = tid & 3;
    const float* Ar = A  + (size_t)(b * 64 + m) * 256 + seg * 64;
    const float* Br = Bm + (size_t)(b * 64 + local) * 256 + seg * 64;
    const float* Cr = Cq + (size_t)b * 256 + seg * 64;
    #pragma unroll
    for (int it = 0; it < 8; ++it) {
      const float4 a0 = *(const float4*)(Ar + it * 8);
      const float4 a1 = *(const float4*)(Ar + it * 8 + 4);
      const float4 b0 = *(const float4*)(Br + it * 8);
      const float4 b1 = *(const float4*)(Br + it * 8 + 4);
      const float4 c0 = *(const float4*)(Cr + it * 8);
      const float4 c1 = *(const float4*)(Cr + it * 8 + 4);
      uint4 pk;
      pk.x = pk2(fmaxf(a0.x + b0.x + c0.x, 0.f), fmaxf(a0.y + b0.y + c0.y, 0.f));
      pk.y = pk2(fmaxf(a0.z + b0.z + c0.z, 0.f), fmaxf(a0.w + b0.w + c0.w, 0.f));
      pk.z = pk2(fmaxf(a1.x + b1.x + c1.x, 0.f), fmaxf(a1.y + b1.y + c1.y, 0.f));
      pk.w = pk2(fmaxf(a1.z + b1.z + c1.z, 0.f), fmaxf(a1.w + b1.w + c1.w, 0.f));
      const int kb = seg * 128 + it * 16;
      *(uint4*)(hbase + (size_t)m * 512 + (kb ^ ((m & 7) << 4))) = pk;
    }
  }
  __syncthreads();

  const unsigned short* wts[3] = {wt2, wt3, wt4};
  const float* bs[3] = {b2, b3, b4};

  for (int layer = 0; layer < 3; ++layer) {
    // per-lane W base: row (n) = cg*64 + l15, k offset l4*8
    const unsigned short* wtg = wts[layer] + (size_t)(cg * 64 + l15) * 256 + l4 * 8;
    f32x4_t acc[4][4];
    #pragma unroll
    for (int a = 0; a < 4; ++a) {
      const float4 bv = *(const float4*)(bs[layer] + cg * 64 + a * 16 + l4 * 4);
      #pragma unroll
      for (int t = 0; t < 4; ++t) {
        acc[a][t][0] = bv.x; acc[a][t][1] = bv.y;
        acc[a][t][2] = bv.z; acc[a][t][3] = bv.w;
      }
    }
    bf16x8_t af[8][4];
    #pragma unroll
    for (int a = 0; a < 4; ++a)
      af[0][a] = *(const bf16x8_t*)(wtg + a * 4096);
    #pragma unroll
    for (int a = 0; a < 4; ++a)
      af[1][a] = *(const bf16x8_t*)(wtg + 32 + a * 4096);
    #pragma unroll
    for (int ks = 0; ks < 8; ++ks) {
      if (ks < 6) {
        #pragma unroll
        for (int a = 0; a < 4; ++a)
          af[ks + 2][a] = *(const bf16x8_t*)(wtg + (ks + 2) * 32 + a * 4096);
      }
      bf16x8_t bf[4];
      #pragma unroll
      for (int t = 0; t < 4; ++t) {
        const int row = t * 16 + l15;
        const int kb = ks * 64 + l4 * 16;
        bf[t] = *(const bf16x8_t*)(hbase + (size_t)row * 512 + (kb ^ ((row & 7) << 4)));
      }
      #pragma unroll
      for (int a = 0; a < 4; ++a)
        #pragma unroll
        for (int t = 0; t < 4; ++t)
          acc[a][t] = __builtin_amdgcn_mfma_f32_16x16x32_bf16(af[ks][a], bf[t], acc[a][t], 0, 0, 0);
    }

    if (layer < 2) {
      __syncthreads();   // all reads of h done before overwriting
      #pragma unroll
      for (int a = 0; a < 4; ++a) {
        #pragma unroll
        for (int t = 0; t < 4; ++t) {
          const int row = t * 16 + l15;
          const int n0 = cg * 64 + a * 16 + l4 * 4;
          uint2 v;
          v.x = pk2(fmaxf(acc[a][t][0], 0.f), fmaxf(acc[a][t][1], 0.f));
          v.y = pk2(fmaxf(acc[a][t][2], 0.f), fmaxf(acc[a][t][3], 0.f));
          *(uint2*)(hbase + (size_t)row * 512 + ((n0 * 2) ^ ((row & 7) << 4))) = v;
        }
      }
      __syncthreads();   // writes visible before next layer reads
    } else {
      #pragma unroll
      for (int a = 0; a < 4; ++a) {
        f32x4_t s;
        s[0] = s[1] = s[2] = s[3] = 0.f;
        #pragma unroll
        for (int t = 0; t < 4; ++t) {
          s[0] += fmaxf(acc[a][t][0], 0.f);
          s[1] += fmaxf(acc[a][t][1], 0.f);
          s[2] += fmaxf(acc[a][t][2], 0.f);
          s[3] += fmaxf(acc[a][t][3], 0.f);
        }
        #pragma unroll
        for (int d = 1; d < 16; d <<= 1) {
          s[0] += __shfl_xor(s[0], d, 64);
          s[1] += __shfl_xor(s[1], d, 64);
          s[2] += __shfl_xor(s[2], d, 64);
          s[3] += __shfl_xor(s[3], d, 64);
        }
        if (l15 == 0)
          *(f32x4_t*)(&gpart[cg * 64 + a * 16 + l4 * 4]) = s;
      }
      __syncthreads();
      atomicAdd(&g[(size_t)b * 256 + tid], gpart[tid]);
    }
  }
}

// ---------------------------------------------------------------------------
// f-network + softmax. One block per batch element.
// ---------------------------------------------------------------------------
__global__ __launch_bounds__(256) void fnet(
    const float* __restrict__ g,
    const float* __restrict__ fw1, const float* __restrict__ fb1,
    const float* __restrict__ fw2, const float* __restrict__ fb2,
    const float* __restrict__ fw3, const float* __restrict__ fb3,
    float* __restrict__ out)
{
  const int b = blockIdx.x, t = threadIdx.x;
  __shared__ float s0[256], s1[256], lg[10];
  s0[t] = g[b * 256 + t];
  __syncthreads();
  float acc = fb1[t];
  for (int k = 0; k < 256; ++k) acc += s0[k] * fw1[k * 256 + t];
  s1[t] = fmaxf(acc, 0.f);
  __syncthreads();
  acc = fb2[t];
  for (int k = 0; k < 256; ++k) acc += s1[k] * fw2[k * 256 + t];
  s0[t] = fmaxf(acc, 0.f);
  __syncthreads();
  if (t < 10) {
    float a = fb3[t];
    for (int k = 0; k < 256; ++k) a += s0[k] * fw3[k * 10 + t];
    lg[t] = a;
  }
  __syncthreads();
  if (t == 0) {
    float m = lg[0];
    for (int c = 1; c < 10; ++c) m = fmaxf(m, lg[c]);
    float e[10], sum = 0.f;
    for (int c = 0; c < 10; ++c) { e[c] = expf(lg[c] - m); sum += e[c]; }
    const float inv = 1.f / sum;
    for (int c = 0; c < 10; ++c) out[b * 10 + c] = e[c] * inv;
  }
}

// ---------------------------------------------------------------------------
extern "C" void kernel_launch(void* const* d_in, const int* in_sizes, int n_in,
                              void* d_out, int out_size, void* d_ws, size_t ws_size,
                              hipStream_t stream)
{
  const float* img = (const float*)d_in[0];
  const float* qst = (const float*)d_in[1];
  const float* cw[4] = {(const float*)d_in[2],  (const float*)d_in[6],
                        (const float*)d_in[10], (const float*)d_in[14]};
  const float* cb[4] = {(const float*)d_in[3],  (const float*)d_in[7],
                        (const float*)d_in[11], (const float*)d_in[15]};
  const float* bg[4] = {(const float*)d_in[4],  (const float*)d_in[8],
                        (const float*)d_in[12], (const float*)d_in[16]};
  const float* bb[4] = {(const float*)d_in[5],  (const float*)d_in[9],
                        (const float*)d_in[13], (const float*)d_in[17]};
  const float* gw1 = (const float*)d_in[18];
  const float* gb1 = (const float*)d_in[19];
  const float* gw2 = (const float*)d_in[20];
  const float* gb2 = (const float*)d_in[21];
  const float* gw3 = (const float*)d_in[22];
  const float* gb3 = (const float*)d_in[23];
  const float* gw4 = (const float*)d_in[24];
  const float* gb4 = (const float*)d_in[25];
  const float* fw1 = (const float*)d_in[26];
  const float* fb1 = (const float*)d_in[27];
  const float* fw2 = (const float*)d_in[28];
  const float* fb2 = (const float*)d_in[29];
  const float* fw3 = (const float*)d_in[30];
  const float* fb3 = (const float*)d_in[31];
  float* out = (float*)d_out;

  float* ws    = (float*)d_ws;
  float* x1    = ws;                  // 6291456
  float* x2    = x1 + 6291456;        // 1572864
  float* x3    = x2 + 1572864;        // 393216
  float* x4    = x3 + 393216;         // 98304
  float* Abuf  = x4 + 98304;          // 1048576
  float* Bbuf  = Abuf + 1048576;      // 1048576
  float* Cqb   = Bbuf + 1048576;      // 16384
  float* gbuf  = Cqb + 16384;         // 16384
  float* stats = gbuf + 16384;        // 192
  unsigned short* wtb = (unsigned short*)(stats + 192);
  unsigned short* wt2 = wtb;
  unsigned short* wt3 = wtb + 65536;
  unsigned short* wt4 = wtb + 131072;

  hipMemsetAsync(gbuf, 0, (16384 + 192) * sizeof(float), stream);

  convk<3, 128, 128, false><<<1536, 256, 0, stream>>>(
      img, cw[0], cb[0], nullptr, nullptr, nullptr, x1, stats + 0);
  convk<24, 64, 64, true><<<1536, 256, 0, stream>>>(
      x1, cw[1], cb[1], stats + 0, bg[0], bb[0], x2, stats + 48);
  convk<24, 32, 32, true><<<1536, 256, 0, stream>>>(
      x2, cw[2], cb[2], stats + 48, bg[1], bb[1], x3, stats + 96);
  convk<24, 16, 16, true><<<1536, 256, 0, stream>>>(
      x3, cw[3], cb[3], stats + 96, bg[2], bb[2], x4, stats + 144);

  build_ab<<<4096, 256, 0, stream>>>(x4, stats + 144, bg[3], bb[3], gw1,
                                     Abuf, Bbuf);
  build_cq<<<64, 256, 0, stream>>>(qst, gw1, gb1, Cqb);
  wt_convert3<<<192, 256, 0, stream>>>(gw2, gw3, gw4, wtb);

  pair_mfma<<<4096, 256, 0, stream>>>(Abuf, Bbuf, Cqb, wt2, gb2, wt3, gb3,
                                      wt4, gb4, gbuf);
  fnet<<<64, 256, 0, stream>>>(gbuf, fw1, fb1, fw2, fb2, fw3, fb3, out);
}

// Round 4
// 788.318 us; speedup vs baseline: 2.1668x; 2.1668x over previous
//
#include <hip/hip_runtime.h>
#include <hip/hip_bf16.h>

typedef __attribute__((ext_vector_type(8))) short bf16x8_t;
typedef __attribute__((ext_vector_type(4))) float f32x4_t;

__device__ __forceinline__ unsigned bfr(float x) {
  unsigned u = __builtin_bit_cast(unsigned, x);
  return (u + 0x7fffu + ((u >> 16) & 1u)) >> 16;
}
__device__ __forceinline__ unsigned pk2(float lo, float hi) {
  return bfr(lo) | (bfr(hi) << 16);
}

// ---------------------------------------------------------------------------
// Conv 3x3 stride2 pad1 + bias + relu + per-channel sum/sumsq stats.
// Block = (BPB batches, OHS output rows). Each thread owns ONE output pixel
// and computes ALL 24 output channels (input staged once per ci, reused 24x).
// BN of the input is applied AT STAGE TIME (x*sc+sh, zero-padded) — exact
// reference semantics. Weights read via wave-uniform indices -> SGPR loads.
// ---------------------------------------------------------------------------
template<int CIN, int H, int OHS, int BPB, bool BNIN>
__global__ __launch_bounds__(256) void convk(
    const float* __restrict__ x, const float* __restrict__ wgt,
    const float* __restrict__ bias,
    const float* __restrict__ instats,
    const float* __restrict__ ing, const float* __restrict__ inb,
    float* __restrict__ y, float* __restrict__ stats)
{
  constexpr int W = H, HO = H / 2, WO = W / 2;
  constexpr int NR = 2 * OHS + 1;          // input rows per strip
  constexpr int TW = W + 1;                // +1 left zero-pad column
  constexpr int SPB = HO / OHS;            // strips per image
  constexpr int NSTG = BPB * NR * W;       // staged elems per ci

  __shared__ float tile[2][BPB][NR][TW];
  __shared__ float scb[CIN], shb[CIN];
  __shared__ float sred[24], sqd[24];

  const int tid = threadIdx.x;
  const int b0 = (blockIdx.x / SPB) * BPB;
  const int strip = blockIdx.x % SPB;
  const int oh0 = strip * OHS;

  if (BNIN && tid < CIN) {
    const float cnt = 64.f * H * W;
    const float m = instats[tid] / cnt;
    const float v = instats[24 + tid] / cnt - m * m;
    const float s = rsqrtf(v + 1e-5f) * ing[tid];
    scb[tid] = s;
    shb[tid] = inb[tid] - m * s;
  }
  if (tid < 24) { sred[tid] = 0.f; sqd[tid] = 0.f; }
  // zero the left pad column of both buffers (never written by staging)
  for (int i = tid; i < 2 * BPB * NR; i += 256) {
    const int bufi = i / (BPB * NR), rem = i % (BPB * NR);
    tile[bufi][rem / NR][rem % NR][0] = 0.f;
  }
  __syncthreads();

  const int ow  = tid % WO;
  const int ohl = (tid / WO) % OHS;
  const int bs  = tid / (WO * OHS);
  const int oh  = oh0 + ohl;

  float acc[24];
  #pragma unroll
  for (int co = 0; co < 24; ++co) acc[co] = bias[co];

  // stage channel 0
  {
    const float sc = BNIN ? scb[0] : 1.f, sh = BNIN ? shb[0] : 0.f;
    for (int idx = tid; idx < NSTG; idx += 256) {
      const int c = idx % W, rr = idx / W;
      const int rl = rr % NR, sb = rr / NR;
      const int ih = oh0 * 2 - 1 + rl;
      float v = 0.f;
      if (ih >= 0)
        v = x[((size_t)((b0 + sb) * CIN + 0) * H + ih) * W + c] * sc + sh;
      else if (BNIN) v = sh;  // ih<0 is zero-pad: pad is on BN OUTPUT -> 0
      if (ih < 0) v = 0.f;
      tile[0][sb][rl][c + 1] = v;
    }
  }
  __syncthreads();

  for (int ci = 0; ci < CIN; ++ci) {
    // prefetch-stage ci+1 into the other buffer (no barrier needed yet:
    // it writes buf (ci+1)&1 which was last read at ci-1, already fenced)
    if (ci + 1 < CIN) {
      const float sc = BNIN ? scb[ci + 1] : 1.f, sh = BNIN ? shb[ci + 1] : 0.f;
      for (int idx = tid; idx < NSTG; idx += 256) {
        const int c = idx % W, rr = idx / W;
        const int rl = rr % NR, sb = rr / NR;
        const int ih = oh0 * 2 - 1 + rl;
        float v = 0.f;
        if (ih >= 0)
          v = x[((size_t)((b0 + sb) * CIN + ci + 1) * H + ih) * W + c] * sc + sh;
        tile[(ci + 1) & 1][sb][rl][c + 1] = v;
      }
    }
    // taps for this thread's pixel
    float tp[9];
    #pragma unroll
    for (int r = 0; r < 3; ++r)
      #pragma unroll
      for (int s = 0; s < 3; ++s)
        tp[r * 3 + s] = tile[ci & 1][bs][2 * ohl + r][2 * ow + s];
    #pragma unroll
    for (int co = 0; co < 24; ++co) {
      const float* wp = wgt + (size_t)(co * CIN + ci) * 9;
      float a = acc[co];
      #pragma unroll
      for (int k = 0; k < 9; ++k) a += tp[k] * wp[k];
      acc[co] = a;
    }
    __syncthreads();
  }

  // relu + store + stats
  const int lane = tid & 63;
  #pragma unroll
  for (int co = 0; co < 24; ++co) {
    const float v = fmaxf(acc[co], 0.f);
    acc[co] = v;
    y[((size_t)((b0 + bs) * 24 + co) * HO + oh) * WO + ow] = v;
  }
  #pragma unroll
  for (int co = 0; co < 24; ++co) {
    float v = acc[co], q = v * v;
    #pragma unroll
    for (int d = 1; d < 64; d <<= 1) {
      v += __shfl_xor(v, d, 64);
      q += __shfl_xor(q, d, 64);
    }
    if (lane == 0) {
      atomicAdd(&sred[co], v);
      atomicAdd(&sqd[co], q);
    }
  }
  __syncthreads();
  if (tid < 24) {
    atomicAdd(&stats[tid], sred[tid]);
    atomicAdd(&stats[24 + tid], sqd[tid]);
  }
}

// ---------------------------------------------------------------------------
// Build A = o @ Wi, B = o @ Wj (BN of x4 fused into o), Cq = qst@Wq + gb1.
// ---------------------------------------------------------------------------
__global__ __launch_bounds__(256) void build_ab(
    const float* __restrict__ x4, const float* __restrict__ stats4,
    const float* __restrict__ g4, const float* __restrict__ b4,
    const float* __restrict__ gw1,
    float* __restrict__ A, float* __restrict__ Bm)
{
  const int bp = blockIdx.x;
  const int b = bp >> 6, p = bp & 63;
  const int t = threadIdx.x;
  __shared__ float o[26];
  if (t < 24) {
    const float m = stats4[t] * (1.f / 4096.f);
    const float v = stats4[24 + t] * (1.f / 4096.f) - m * m;
    const float sc = rsqrtf(v + 1e-5f) * g4[t];
    const float sh = b4[t] - m * sc;
    o[t] = x4[(size_t)(b * 24 + t) * 64 + p] * sc + sh;
  } else if (t == 24) o[24] = (float)(p >> 3);
  else if (t == 25) o[25] = (float)(p & 7);
  __syncthreads();
  float a = 0.f, bb2 = 0.f;
  #pragma unroll
  for (int c = 0; c < 26; ++c) {
    a   += o[c] * gw1[c * 256 + t];
    bb2 += o[c] * gw1[(26 + c) * 256 + t];
  }
  A[(size_t)bp * 256 + t]  = a;
  Bm[(size_t)bp * 256 + t] = bb2;
}

__global__ __launch_bounds__(256) void build_cq(
    const float* __restrict__ qst, const float* __restrict__ gw1,
    const float* __restrict__ gb1, float* __restrict__ Cq)
{
  const int b = blockIdx.x, t = threadIdx.x;
  float a = gb1[t];
  #pragma unroll
  for (int c = 0; c < 11; ++c) a += qst[b * 11 + c] * gw1[(52 + c) * 256 + t];
  Cq[b * 256 + t] = a;
}

// ---------------------------------------------------------------------------
// Transpose-convert the 3 W matrices (fp32 [k][n]) -> bf16 [n][k]. Grid 192.
// ---------------------------------------------------------------------------
__global__ __launch_bounds__(256) void wt_convert3(
    const float* __restrict__ W2, const float* __restrict__ W3,
    const float* __restrict__ W4, unsigned short* __restrict__ wt)
{
  const int which = blockIdx.x >> 6;
  const float* W = which == 0 ? W2 : which == 1 ? W3 : W4;
  unsigned short* o = wt + (size_t)which * 65536;
  __shared__ float ts[32][33];
  const int blk = blockIdx.x & 63;
  const int k0 = (blk & 7) * 32, n0 = (blk >> 3) * 32;
  const int t = threadIdx.x;
  const int r = t >> 3, c4 = (t & 7) * 4;
  const float4 v = *(const float4*)(W + (size_t)(k0 + r) * 256 + n0 + c4);
  ts[r][c4 + 0] = v.x; ts[r][c4 + 1] = v.y;
  ts[r][c4 + 2] = v.z; ts[r][c4 + 3] = v.w;
  __syncthreads();
  uint2 ov;
  ov.x = pk2(ts[c4 + 0][r], ts[c4 + 1][r]);
  ov.y = pk2(ts[c4 + 2][r], ts[c4 + 3][r]);
  *(uint2*)(o + (size_t)(n0 + r) * 256 + k0 + c4) = ov;
}

// ---------------------------------------------------------------------------
// Pair MLP via MFMA. 4 waves / 64 rows / 256 cols per block, 2 blocks/CU.
// W staged in LDS (80B-padded rows, double-buffered, prefetch chained across
// the 3 layers = 24 chunks). h in 32KB XOR-swizzled LDS. No global atomics:
// per-block partial written to Gpart, reduced by reduce_g.
// ---------------------------------------------------------------------------
__global__ __launch_bounds__(256) void pair_mfma(
    const float* __restrict__ A, const float* __restrict__ Bm,
    const float* __restrict__ Cq,
    const unsigned short* __restrict__ wtall,
    const float* __restrict__ b2, const float* __restrict__ b3,
    const float* __restrict__ b4,
    float* __restrict__ Gpart)
{
  __shared__ __align__(16) unsigned short hsm[64 * 256];        // 32 KB
  __shared__ __align__(16) unsigned short wbuf[2][256 * 40];    // 40 KB
  __shared__ float gpart[256];

  const int tid = threadIdx.x;
  int bid = blockIdx.x;
  bid = (bid & 7) * 512 + (bid >> 3);      // XCD swizzle (4096 = 8*512)
  const int b = bid >> 6, local = bid & 63;
  const int lane = tid & 63, cg = tid >> 6;
  const int l15 = lane & 15, l4 = lane >> 4;
  char* hbase = (char*)hsm;

  // staging geometry: thread covers rows {r0, r0+64, r0+128, r0+192}, slot ss
  const int r0 = tid >> 2, ss = tid & 3;

  // ---- build h1 = relu(A_i + B_j + Cq) bf16, swizzled
  {
    const int m = tid >> 2, seg = tid & 3;
    const float* Ar = A  + (size_t)(b * 64 + m) * 256 + seg * 64;
    const float* Br = Bm + (size_t)(b * 64 + local) * 256 + seg * 64;
    const float* Cr = Cq + (size_t)b * 256 + seg * 64;
    #pragma unroll
    for (int it = 0; it < 8; ++it) {
      const float4 a0 = *(const float4*)(Ar + it * 8);
      const float4 a1 = *(const float4*)(Ar + it * 8 + 4);
      const float4 b0 = *(const float4*)(Br + it * 8);
      const float4 b1 = *(const float4*)(Br + it * 8 + 4);
      const float4 c0 = *(const float4*)(Cr + it * 8);
      const float4 c1 = *(const float4*)(Cr + it * 8 + 4);
      uint4 pk;
      pk.x = pk2(fmaxf(a0.x + b0.x + c0.x, 0.f), fmaxf(a0.y + b0.y + c0.y, 0.f));
      pk.y = pk2(fmaxf(a0.z + b0.z + c0.z, 0.f), fmaxf(a0.w + b0.w + c0.w, 0.f));
      pk.z = pk2(fmaxf(a1.x + b1.x + c1.x, 0.f), fmaxf(a1.y + b1.y + c1.y, 0.f));
      pk.w = pk2(fmaxf(a1.z + b1.z + c1.z, 0.f), fmaxf(a1.w + b1.w + c1.w, 0.f));
      const int kb = seg * 128 + it * 16;
      *(uint4*)(hbase + (size_t)m * 512 + (kb ^ ((m & 7) << 4))) = pk;
    }
  }

  // ---- stage chunk 0 (layer 0, ks 0)
  {
    #pragma unroll
    for (int q = 0; q < 4; ++q) {
      const int n = r0 + q * 64;
      const uint4 v = *(const uint4*)(wtall + (size_t)n * 256 + ss * 8);
      *(uint4*)(wbuf[0] + n * 40 + ss * 8) = v;
    }
  }
  __syncthreads();

  const float* bs3[3] = {b2, b3, b4};

  for (int layer = 0; layer < 3; ++layer) {
    f32x4_t acc[4][4];
    #pragma unroll
    for (int a = 0; a < 4; ++a) {
      const float4 bv = *(const float4*)(bs3[layer] + cg * 64 + a * 16 + l4 * 4);
      #pragma unroll
      for (int t = 0; t < 4; ++t) {
        acc[a][t][0] = bv.x; acc[a][t][1] = bv.y;
        acc[a][t][2] = bv.z; acc[a][t][3] = bv.w;
      }
    }
    for (int ks = 0; ks < 8; ++ks) {
      const int c = layer * 8 + ks;
      uint4 p0, p1, p2, p3;
      if (c + 1 < 24) {
        const unsigned short* src =
            wtall + (size_t)((c + 1) >> 3) * 65536 + ((c + 1) & 7) * 32;
        p0 = *(const uint4*)(src + (size_t)(r0)       * 256 + ss * 8);
        p1 = *(const uint4*)(src + (size_t)(r0 + 64)  * 256 + ss * 8);
        p2 = *(const uint4*)(src + (size_t)(r0 + 128) * 256 + ss * 8);
        p3 = *(const uint4*)(src + (size_t)(r0 + 192) * 256 + ss * 8);
      }
      bf16x8_t bf[4];
      #pragma unroll
      for (int t = 0; t < 4; ++t) {
        const int row = t * 16 + l15;
        const int kb = ks * 64 + l4 * 16;
        bf[t] = *(const bf16x8_t*)(hbase + (size_t)row * 512 + (kb ^ ((row & 7) << 4)));
      }
      const unsigned short* wrd = wbuf[c & 1];
      #pragma unroll
      for (int a = 0; a < 4; ++a) {
        const bf16x8_t af = *(const bf16x8_t*)(wrd + (cg * 64 + a * 16 + l15) * 40 + l4 * 8);
        #pragma unroll
        for (int t = 0; t < 4; ++t)
          acc[a][t] = __builtin_amdgcn_mfma_f32_16x16x32_bf16(af, bf[t], acc[a][t], 0, 0, 0);
      }
      if (c + 1 < 24) {
        unsigned short* wb = wbuf[(c + 1) & 1];
        *(uint4*)(wb + (r0)       * 40 + ss * 8) = p0;
        *(uint4*)(wb + (r0 + 64)  * 40 + ss * 8) = p1;
        *(uint4*)(wb + (r0 + 128) * 40 + ss * 8) = p2;
        *(uint4*)(wb + (r0 + 192) * 40 + ss * 8) = p3;
      }
      __syncthreads();
    }

    if (layer < 2) {
      // write back relu(h_next) as bf16 (all h reads of this layer are fenced
      // by the last ks barrier)
      #pragma unroll
      for (int a = 0; a < 4; ++a) {
        #pragma unroll
        for (int t = 0; t < 4; ++t) {
          const int row = t * 16 + l15;
          const int n0 = cg * 64 + a * 16 + l4 * 4;
          uint2 v;
          v.x = pk2(fmaxf(acc[a][t][0], 0.f), fmaxf(acc[a][t][1], 0.f));
          v.y = pk2(fmaxf(acc[a][t][2], 0.f), fmaxf(acc[a][t][3], 0.f));
          *(uint2*)(hbase + (size_t)row * 512 + ((n0 * 2) ^ ((row & 7) << 4))) = v;
        }
      }
      __syncthreads();
    } else {
      #pragma unroll
      for (int a = 0; a < 4; ++a) {
        f32x4_t s;
        s[0] = s[1] = s[2] = s[3] = 0.f;
        #pragma unroll
        for (int t = 0; t < 4; ++t) {
          s[0] += fmaxf(acc[a][t][0], 0.f);
          s[1] += fmaxf(acc[a][t][1], 0.f);
          s[2] += fmaxf(acc[a][t][2], 0.f);
          s[3] += fmaxf(acc[a][t][3], 0.f);
        }
        #pragma unroll
        for (int d = 1; d < 16; d <<= 1) {
          s[0] += __shfl_xor(s[0], d, 64);
          s[1] += __shfl_xor(s[1], d, 64);
          s[2] += __shfl_xor(s[2], d, 64);
          s[3] += __shfl_xor(s[3], d, 64);
        }
        if (l15 == 0)
          *(f32x4_t*)(&gpart[cg * 64 + a * 16 + l4 * 4]) = s;
      }
      __syncthreads();
      Gpart[(size_t)(b * 64 + local) * 256 + tid] = gpart[tid];
    }
  }
}

__global__ __launch_bounds__(256) void reduce_g(
    const float* __restrict__ Gpart, float* __restrict__ g)
{
  const int b = blockIdx.x, t = threadIdx.x;
  float s = 0.f;
  for (int j = 0; j < 64; ++j) s += Gpart[(size_t)(b * 64 + j) * 256 + t];
  g[b * 256 + t] = s;
}

// ---------------------------------------------------------------------------
// f-network + softmax. One block per batch element.
// ---------------------------------------------------------------------------
__global__ __launch_bounds__(256) void fnet(
    const float* __restrict__ g,
    const float* __restrict__ fw1, const float* __restrict__ fb1,
    const float* __restrict__ fw2, const float* __restrict__ fb2,
    const float* __restrict__ fw3, const float* __restrict__ fb3,
    float* __restrict__ out)
{
  const int b = blockIdx.x, t = threadIdx.x;
  __shared__ float s0[256], s1[256], lg[10];
  s0[t] = g[b * 256 + t];
  __syncthreads();
  float acc = fb1[t];
  for (int k = 0; k < 256; ++k) acc += s0[k] * fw1[k * 256 + t];
  s1[t] = fmaxf(acc, 0.f);
  __syncthreads();
  acc = fb2[t];
  for (int k = 0; k < 256; ++k) acc += s1[k] * fw2[k * 256 + t];
  s0[t] = fmaxf(acc, 0.f);
  __syncthreads();
  if (t < 10) {
    float a = fb3[t];
    for (int k = 0; k < 256; ++k) a += s0[k] * fw3[k * 10 + t];
    lg[t] = a;
  }
  __syncthreads();
  if (t == 0) {
    float m = lg[0];
    for (int c = 1; c < 10; ++c) m = fmaxf(m, lg[c]);
    float e[10], sum = 0.f;
    for (int c = 0; c < 10; ++c) { e[c] = expf(lg[c] - m); sum += e[c]; }
    const float inv = 1.f / sum;
    for (int c = 0; c < 10; ++c) out[b * 10 + c] = e[c] * inv;
  }
}

// ---------------------------------------------------------------------------
extern "C" void kernel_launch(void* const* d_in, const int* in_sizes, int n_in,
                              void* d_out, int out_size, void* d_ws, size_t ws_size,
                              hipStream_t stream)
{
  const float* img = (const float*)d_in[0];
  const float* qst = (const float*)d_in[1];
  const float* cw[4] = {(const float*)d_in[2],  (const float*)d_in[6],
                        (const float*)d_in[10], (const float*)d_in[14]};
  const float* cb[4] = {(const float*)d_in[3],  (const float*)d_in[7],
                        (const float*)d_in[11], (const float*)d_in[15]};
  const float* bg[4] = {(const float*)d_in[4],  (const float*)d_in[8],
                        (const float*)d_in[12], (const float*)d_in[16]};
  const float* bb[4] = {(const float*)d_in[5],  (const float*)d_in[9],
                        (const float*)d_in[13], (const float*)d_in[17]};
  const float* gw1 = (const float*)d_in[18];
  const float* gb1 = (const float*)d_in[19];
  const float* gw2 = (const float*)d_in[20];
  const float* gb2 = (const float*)d_in[21];
  const float* gw3 = (const float*)d_in[22];
  const float* gb3 = (const float*)d_in[23];
  const float* gw4 = (const float*)d_in[24];
  const float* gb4 = (const float*)d_in[25];
  const float* fw1 = (const float*)d_in[26];
  const float* fb1 = (const float*)d_in[27];
  const float* fw2 = (const float*)d_in[28];
  const float* fb2 = (const float*)d_in[29];
  const float* fw3 = (const float*)d_in[30];
  const float* fb3 = (const float*)d_in[31];
  float* out = (float*)d_out;

  float* ws    = (float*)d_ws;
  float* x1    = ws;                  // 6291456
  float* x2    = x1 + 6291456;        // 1572864
  float* x3    = x2 + 1572864;        // 393216
  float* x4    = x3 + 393216;         // 98304
  float* Abuf  = x4 + 98304;          // 1048576
  float* Bbuf  = Abuf + 1048576;      // 1048576
  float* Cqb   = Bbuf + 1048576;      // 16384
  float* Gpart = Cqb + 16384;         // 1048576
  float* gbuf  = Gpart + 1048576;     // 16384
  float* stats = gbuf + 16384;        // 192
  unsigned short* wtb = (unsigned short*)(stats + 192);

  hipMemsetAsync(stats, 0, 192 * sizeof(float), stream);

  convk<3, 128, 4, 1, false><<<1024, 256, 0, stream>>>(
      img, cw[0], cb[0], nullptr, nullptr, nullptr, x1, stats + 0);
  convk<24, 64, 8, 1, true><<<256, 256, 0, stream>>>(
      x1, cw[1], cb[1], stats + 0, bg[0], bb[0], x2, stats + 48);
  convk<24, 32, 16, 1, true><<<64, 256, 0, stream>>>(
      x2, cw[2], cb[2], stats + 48, bg[1], bb[1], x3, stats + 96);
  convk<24, 16, 8, 4, true><<<16, 256, 0, stream>>>(
      x3, cw[3], cb[3], stats + 96, bg[2], bb[2], x4, stats + 144);

  build_ab<<<4096, 256, 0, stream>>>(x4, stats + 144, bg[3], bb[3], gw1,
                                     Abuf, Bbuf);
  build_cq<<<64, 256, 0, stream>>>(qst, gw1, gb1, Cqb);
  wt_convert3<<<192, 256, 0, stream>>>(gw2, gw3, gw4, wtb);

  pair_mfma<<<4096, 256, 0, stream>>>(Abuf, Bbuf, Cqb, wtb, gb2, gb3, gb4,
                                      Gpart);
  reduce_g<<<64, 256, 0, stream>>>(Gpart, gbuf);
  fnet<<<64, 256, 0, stream>>>(gbuf, fw1, fb1, fw2, fb2, fw3, fb3, out);
}